// Round 2
// baseline (196.612 us; speedup 1.0000x reference)
//
#include <hip/hip_runtime.h>

// HMULayer omega: out[b][n] = exp(-(lam_n*||x_b-mu_n||^2 + sum_k om_nk*((x_b-mu_n).v_nk)^2)/D)
// B=1024, N=8192, D=256, K=8. Strategy: 9 fused bf16 MFMA GEMMs sharing A=x,
// per-lane epilogue (C/D layout identical across the 9 accumulators).

#define B_SZ 1024
#define N_SZ 8192
#define D_SZ 256
#define K_SZ 8

#define BT 128          // b-tile per block
#define NT 16           // n-tile per block
#define LDS_STRIDE 40   // 32 bf16 + 8 pad -> 80B row stride, 2-way bank aliasing (free)

typedef __bf16 bf16x8 __attribute__((ext_vector_type(8)));
typedef float f32x4 __attribute__((ext_vector_type(4)));
typedef unsigned short u16x8 __attribute__((ext_vector_type(8)));

__device__ __forceinline__ float wave_reduce(float s) {
#pragma unroll
  for (int off = 32; off > 0; off >>= 1) s += __shfl_down(s, off);
  return s;
}

// P1: x2[b] = sum_d x[b][d]^2   (grid=1024, block=64)
__global__ void p1_x2(const float* __restrict__ x, float* __restrict__ x2) {
  const int b = blockIdx.x, l = threadIdx.x;
  const float* xr = x + (size_t)b * D_SZ;
  float s = 0.f;
#pragma unroll
  for (int i = 0; i < 4; ++i) { float f = xr[l + 64 * i]; s += f * f; }
  s = wave_reduce(s);
  if (l == 0) x2[b] = s;
}

// P2: mu2[n], muv[n][k]   (grid=8192, block=64)
__global__ void p2_mu(const float* __restrict__ mu, const float* __restrict__ v,
                      float* __restrict__ mu2, float* __restrict__ muv) {
  const int n = blockIdx.x, l = threadIdx.x;
  const float* mr = mu + (size_t)n * D_SZ;
  float md[4];
  float m2 = 0.f;
#pragma unroll
  for (int i = 0; i < 4; ++i) { md[i] = mr[l + 64 * i]; m2 += md[i] * md[i]; }
  m2 = wave_reduce(m2);
  if (l == 0) mu2[n] = m2;
#pragma unroll
  for (int k = 0; k < K_SZ; ++k) {
    const float* vr = v + (size_t)(n * K_SZ + k) * D_SZ;
    float s = 0.f;
#pragma unroll
    for (int i = 0; i < 4; ++i) s += md[i] * vr[l + 64 * i];
    s = wave_reduce(s);
    if (l == 0) muv[n * K_SZ + k] = s;
  }
}

__device__ __forceinline__ void cvt16_store(const float* __restrict__ src,
                                            unsigned short* dst /* 16B aligned */) {
  const float4* p4 = (const float4*)src;
  float fv[16];
#pragma unroll
  for (int e = 0; e < 4; ++e) {
    float4 t = p4[e];
    fv[4 * e + 0] = t.x; fv[4 * e + 1] = t.y;
    fv[4 * e + 2] = t.z; fv[4 * e + 3] = t.w;
  }
  u16x8 lo, hi;
#pragma unroll
  for (int e = 0; e < 8; ++e) {
    lo[e] = __builtin_bit_cast(unsigned short, (__bf16)fv[e]);
    hi[e] = __builtin_bit_cast(unsigned short, (__bf16)fv[e + 8]);
  }
  *(u16x8*)dst = lo;
  *(u16x8*)(dst + 8) = hi;
}

__global__ __launch_bounds__(256, 2)
void hmu_main(const float* __restrict__ x, const float* __restrict__ mu,
              const float* __restrict__ lam, const float* __restrict__ v,
              const float* __restrict__ om, const float* __restrict__ ws,
              float* __restrict__ out) {
  __shared__ __align__(16) unsigned short As[BT * LDS_STRIDE];      // [b:128][k:32(+8)]
  __shared__ __align__(16) unsigned short Bs[NT * 9 * LDS_STRIDE];  // [n*9+j:144][k:32(+8)]

  const float* ws_x2 = ws;
  const float* ws_mu2 = ws + B_SZ;
  const float* ws_muv = ws + B_SZ + N_SZ;

  const int tid = threadIdx.x;
  const int lane = tid & 63;
  const int w = tid >> 6;       // wave 0..3, owns b-subtiles {2w, 2w+1}
  const int m = lane & 15;      // MFMA row (A) / col (B,n) / col (C)
  const int kg = lane >> 4;     // k-group

  const int n0 = blockIdx.x * NT;
  const int b0 = blockIdx.y * BT;

  f32x4 acc[2][9];
#pragma unroll
  for (int bs = 0; bs < 2; ++bs)
#pragma unroll
    for (int j = 0; j < 9; ++j) acc[bs][j] = (f32x4){0.f, 0.f, 0.f, 0.f};

  const int arow = tid >> 1, ahalf = tid & 1;   // A staging: 2 threads/row

  for (int kt = 0; kt < 8; ++kt) {
    const int k0 = kt * 32;
    // --- stage A: x[b0+row][k0 + half*16 .. +16) ---
    cvt16_store(x + (size_t)(b0 + arow) * D_SZ + k0 + ahalf * 16,
                &As[arow * LDS_STRIDE + ahalf * 16]);
    // --- stage B: 144 rows (n-major: row = n*9 + j; j=0 -> mu, j>=1 -> v[j-1]) ---
#pragma unroll
    for (int it = 0; it < 2; ++it) {
      int idx = tid + 256 * it;
      if (idx < 288) {
        int row = idx >> 1, half = idx & 1;
        int nl = row / 9;
        int j = row - nl * 9;
        const float* src = (j == 0)
            ? mu + (size_t)(n0 + nl) * D_SZ + k0 + half * 16
            : v + (size_t)((n0 + nl) * K_SZ + (j - 1)) * D_SZ + k0 + half * 16;
        cvt16_store(src, &Bs[row * LDS_STRIDE + half * 16]);
      }
    }
    __syncthreads();

    bf16x8 af[2];
#pragma unroll
    for (int bs = 0; bs < 2; ++bs) {
      int r = (2 * w + bs) * 16 + m;
      af[bs] = *(const bf16x8*)&As[r * LDS_STRIDE + kg * 8];
    }
#pragma unroll
    for (int j = 0; j < 9; ++j) {
      bf16x8 bfr = *(const bf16x8*)&Bs[(m * 9 + j) * LDS_STRIDE + kg * 8];
      acc[0][j] = __builtin_amdgcn_mfma_f32_16x16x32_bf16(af[0], bfr, acc[0][j], 0, 0, 0);
      acc[1][j] = __builtin_amdgcn_mfma_f32_16x16x32_bf16(af[1], bfr, acc[1][j], 0, 0, 0);
    }
    __syncthreads();
  }

  // --- epilogue: per-lane, C/D layout col=lane&15 (n), row=kg*4+reg (b) ---
  const int n = n0 + m;
  const float lam_n = lam[n];
  const float mu2_n = ws_mu2[n];
  float omr[8], muvr[8];
#pragma unroll
  for (int k = 0; k < 8; ++k) {
    omr[k] = om[n * 8 + k];
    muvr[k] = ws_muv[n * 8 + k];
  }
#pragma unroll
  for (int bs = 0; bs < 2; ++bs) {
#pragma unroll
    for (int r = 0; r < 4; ++r) {
      int b = b0 + (2 * w + bs) * 16 + kg * 4 + r;
      float x2b = ws_x2[b];
      float c0 = acc[bs][0][r];
      float q = lam_n * (x2b - 2.f * c0 + mu2_n);
#pragma unroll
      for (int k = 0; k < 8; ++k) {
        float p = acc[bs][k + 1][r] - muvr[k];
        q = fmaf(omr[k] * p, p, q);
      }
      out[(size_t)b * N_SZ + n] = __expf(q * (-1.0f / 256.0f));
    }
  }
}

extern "C" void kernel_launch(void* const* d_in, const int* in_sizes, int n_in,
                              void* d_out, int out_size, void* d_ws, size_t ws_size,
                              hipStream_t stream) {
  const float* x   = (const float*)d_in[0];
  const float* mu  = (const float*)d_in[1];
  const float* lam = (const float*)d_in[2];
  const float* v   = (const float*)d_in[3];
  const float* om  = (const float*)d_in[4];
  float* out = (float*)d_out;
  float* ws  = (float*)d_ws;   // [x2:1024][mu2:8192][muv:65536] fp32 = 292KB

  p1_x2<<<B_SZ, 64, 0, stream>>>(x, ws);
  p2_mu<<<N_SZ, 64, 0, stream>>>(mu, v, ws + B_SZ, ws + B_SZ + N_SZ);
  dim3 grid(N_SZ / NT, B_SZ / BT);
  hmu_main<<<grid, 256, 0, stream>>>(x, mu, lam, v, om, ws, out);
}